// Round 7
// baseline (149.227 us; speedup 1.0000x reference)
//
#include <hip/hip_runtime.h>
#include <hip/hip_fp16.h>

#define BATCH 4096
#define LQ 30
#define LD 128
#define EMB 50
#define ROWS 160       // rows 0..29 query, 30..31 pad, 32..159 docs
#define KN 21
#define THREADS 512
#define K10 14.426950408889634f      // 10/ln2
#define C50 72.134752044448169f      // 50/ln2
#define KW  144.26950408889634f      // 100/ln2

typedef __attribute__((ext_vector_type(8))) _Float16 half8;
typedef __attribute__((ext_vector_type(4))) float f32x4;

#define EXP2(x) __builtin_amdgcn_exp2f(x)
// LDS layout: row-major [160][64] fp16 (128 B row), XOR-swizzled at 16B chunks.
// uint-unit address of chunk c of row r:
#define SHW(row, c) (((row) << 5) + ((((c) ^ ((row) & 7))) << 2))

// G_j = exp(-j^2/2), j = k-10 (applied once after pooling)
__device__ __constant__ float Gv[20] = {
  1.928749847963918e-22f, 2.576757109154981e-18f, 1.266416554909418e-14f,
  2.269996488124243e-11f, 1.522997974471263e-08f, 3.726653172078671e-06f,
  3.354626279025119e-04f, 1.110899653824231e-02f, 1.353352832366127e-01f,
  6.065306597126334e-01f, 1.0f,
  6.065306597126334e-01f, 1.353352832366127e-01f, 1.110899653824231e-02f,
  3.354626279025119e-04f, 3.726653172078671e-06f, 1.522997974471263e-08f,
  2.269996488124243e-11f, 1.266416554909418e-14f, 2.576757109154981e-18f
};

__device__ __forceinline__ unsigned pack2(float a, float b) {
  __half2 h = __floats2half2_rn(a, b);
  return *reinterpret_cast<unsigned*>(&h);
}

__global__ __launch_bounds__(THREADS, 8) void knrm_pair_kernel(
    const int* __restrict__ q1, const int* __restrict__ d1,
    const int* __restrict__ q2, const int* __restrict__ d2,
    const float* __restrict__ emb, const float* __restrict__ mlp_w,
    const float* __restrict__ mlp_b, float* __restrict__ logits)
{
  __shared__ unsigned int shw[ROWS * 32];        // 160 rows x 64 fp16 (swizzled)
  __shared__ int toks[ROWS];
  __shared__ float kacc2[2][4][16][KN];          // [qtile][dpair][qcol][kernel]

  const int b = blockIdx.x;
  const int pair = blockIdx.y;
  const int tid = threadIdx.x;
  const int* __restrict__ qp = pair ? q2 : q1;
  const int* __restrict__ dp = pair ? d2 : d1;

  // ---- token ids ----
  if (tid < ROWS) {
    int t = -1;
    if (tid < LQ) t = qp[b * LQ + tid];
    else if (tid >= 32) t = dp[b * LD + (tid - 32)];
    toks[tid] = t;
  }
  __syncthreads();

  // ---- phase 1: 2 threads per row; gather + normalize + fp16 store ----
  if (tid < 2 * ROWS) {
    const int row = tid >> 1;
    const int p = tid & 1;                // p=0: elems 0..23, p=1: 24..49
    const int tok = toks[row];
    float4 e[6];
    float2 tail = make_float2(0.f, 0.f);
    float ss = 0.f;
    if (tok >= 0) {
      const float* bp = emb + (long)tok * EMB + p * 24;
      #pragma unroll
      for (int c = 0; c < 6; ++c) e[c] = *(const float4*)(bp + 4 * c);
      if (p) tail = *(const float2*)(emb + (long)tok * EMB + 48);
      #pragma unroll
      for (int c = 0; c < 6; ++c)
        ss += e[c].x*e[c].x + e[c].y*e[c].y + e[c].z*e[c].z + e[c].w*e[c].w;
      ss += tail.x*tail.x + tail.y*tail.y;
    } else {
      #pragma unroll
      for (int c = 0; c < 6; ++c) e[c] = make_float4(0.f, 0.f, 0.f, 0.f);
    }
    ss += __shfl_xor(ss, 1);
    const float scale = 1.0f / fmaxf(sqrtf(ss), 1e-12f);
    #pragma unroll
    for (int cc = 0; cc < 3; ++cc) {      // 3 full 16B chunks (8 halfs each)
      const float4 a = e[2 * cc], b4 = e[2 * cc + 1];
      uint4 w4;
      w4.x = pack2(a.x * scale, a.y * scale);
      w4.y = pack2(a.z * scale, a.w * scale);
      w4.z = pack2(b4.x * scale, b4.y * scale);
      w4.w = pack2(b4.z * scale, b4.w * scale);
      *(uint4*)&shw[SHW(row, p * 3 + cc)] = w4;
    }
    if (p) {                              // chunk 6: elems 48,49 + zeros; chunk 7: zeros
      uint4 t6 = {pack2(tail.x * scale, tail.y * scale), 0u, 0u, 0u};
      *(uint4*)&shw[SHW(row, 6)] = t6;
      uint4 z = {0u, 0u, 0u, 0u};
      *(uint4*)&shw[SHW(row, 7)] = z;
    }
  }
  __syncthreads();

  // ---- phase 2: wave w = (qtile, dpair); 2 doc-tiles per wave ----
  const int lane = tid & 63;
  const int w = tid >> 6;             // 0..7
  const int qtile = w >> 2;           // 0..1
  const int dpair = w & 3;            // 0..3  -> dtiles {dpair, dpair+4}
  const int col = lane & 15;          // C col = query within tile
  const int kgrp = lane >> 4;         // 0..3

  const int qrow = qtile * 16 + col;
  const half8 Bq0 = *(const half8*)&shw[SHW(qrow, kgrp)];       // k 0..31 slice
  const half8 Bq1 = *(const half8*)&shw[SHW(qrow, 4 + kgrp)];   // k 32..63 slice
  const int qtok = toks[qrow];

  // doc tokens for this lane's 8 output rows (hoisted)
  int dt8[8];
  #pragma unroll
  for (int s = 0; s < 2; ++s)
    #pragma unroll
    for (int r = 0; r < 4; ++r)
      dt8[s * 4 + r] = toks[32 + (dpair + s * 4) * 16 + kgrp * 4 + r];

  float macc[20];                     // unscaled power sums  sum v*T^j, j=k-10
  #pragma unroll
  for (int k = 0; k < 20; ++k) macc[k] = 0.0f;
  float cnt = 0.0f;

  #pragma unroll 1
  for (int s = 0; s < 2; ++s) {
    const int arow = 32 + (dpair + s * 4) * 16 + col;   // A row = doc
    const half8 A0 = *(const half8*)&shw[SHW(arow, kgrp)];
    const half8 A1 = *(const half8*)&shw[SHW(arow, 4 + kgrp)];

    f32x4 acc = {0.0f, 0.0f, 0.0f, 0.0f};
    acc = __builtin_amdgcn_mfma_f32_16x16x32_f16(A0, Bq0, acc, 0, 0, 0);
    acc = __builtin_amdgcn_mfma_f32_16x16x32_f16(A1, Bq1, acc, 0, 0, 0);

    #pragma unroll
    for (int r = 0; r < 4; ++r) {
      const float x = acc[r];
      cnt += (dt8[s * 4 + r] == qtok) ? 1.0f : 0.0f;  // exact-match kernel
      const float t  = x - 0.05f;
      const float tt = t * t;
      const float varg = -C50 * tt;
      const float v = EXP2(varg);                 // e^{-50 t^2}      (j=0)
      const float T = EXP2(K10 * t);              // e^{10 t}
      const float wd = EXP2(fmaf(-KW, t, varg));  // v*T^-10          (j=-10)
      const float T2 = T * T, T3 = T2 * T, T4 = T2 * T2;
      macc[10] += v;
      macc[11] = fmaf(v, T,  macc[11]);
      macc[12] = fmaf(v, T2, macc[12]);
      macc[13] = fmaf(v, T3, macc[13]);
      float pu = v * T4;                          // j=4
      macc[14] += pu;
      macc[15] = fmaf(pu, T,  macc[15]);
      macc[16] = fmaf(pu, T2, macc[16]);
      macc[17] = fmaf(pu, T3, macc[17]);
      pu *= T4;                                   // j=8
      macc[18] += pu;
      macc[19] = fmaf(pu, T,  macc[19]);
      macc[0] += wd;
      macc[1] = fmaf(wd, T,  macc[1]);
      macc[2] = fmaf(wd, T2, macc[2]);
      macc[3] = fmaf(wd, T3, macc[3]);
      float qd = wd * T4;                         // j=-6
      macc[4] += qd;
      macc[5] = fmaf(qd, T,  macc[5]);
      macc[6] = fmaf(qd, T2, macc[6]);
      macc[7] = fmaf(qd, T3, macc[7]);
      qd *= T4;                                   // j=-2
      macc[8] += qd;
      macc[9] = fmaf(qd, T,  macc[9]);
    }
  }

  // cross-kgrp (doc) reduction within the wave, then G_j scaling
  float out_r[KN];
  #pragma unroll
  for (int k = 0; k < 20; ++k) out_r[k] = macc[k];
  out_r[20] = cnt;
  #pragma unroll
  for (int k = 0; k < KN; ++k) {
    out_r[k] += __shfl_xor(out_r[k], 16);
    out_r[k] += __shfl_xor(out_r[k], 32);
  }

  if (lane < 16) {
    #pragma unroll
    for (int k = 0; k < 20; ++k)
      kacc2[qtile][dpair][lane][k] = out_r[k] * Gv[k];
    kacc2[qtile][dpair][lane][20] = out_r[20];
  }
  __syncthreads();

  // ---- final: wave 0 combines 4 doc-slices, applies log1p + MLP ----
  if (tid < 64) {
    float s = 0.0f;
    if (tid < 32) {
      const int qt = tid >> 4, q = tid & 15;
      if (qt * 16 + q < LQ) {
        #pragma unroll
        for (int k = 0; k < KN; ++k) {
          const float S = kacc2[qt][0][q][k] + kacc2[qt][1][q][k] +
                          kacc2[qt][2][q][k] + kacc2[qt][3][q][k];
          s = fmaf(mlp_w[k], __logf(1.0f + S), s);
        }
      }
    }
    s += __shfl_xor(s, 1);
    s += __shfl_xor(s, 2);
    s += __shfl_xor(s, 4);
    s += __shfl_xor(s, 8);
    s += __shfl_xor(s, 16);
    s += __shfl_xor(s, 32);
    if (tid == 0) logits[pair * BATCH + b] = s + mlp_b[0];
  }
}

__global__ void knrm_combine_kernel(const float* __restrict__ logits,
                                    float* __restrict__ out) {
  int i = blockIdx.x * 256 + threadIdx.x;
  if (i < BATCH) {
    float z = logits[i] - logits[BATCH + i];
    out[i] = 1.0f / (1.0f + __expf(-z));
  }
}

extern "C" void kernel_launch(void* const* d_in, const int* in_sizes, int n_in,
                              void* d_out, int out_size, void* d_ws, size_t ws_size,
                              hipStream_t stream) {
  const int* q1 = (const int*)d_in[0];
  const int* d1 = (const int*)d_in[1];
  const int* q2 = (const int*)d_in[2];
  const int* d2 = (const int*)d_in[3];
  const float* emb = (const float*)d_in[4];
  const float* mlp_w = (const float*)d_in[5];
  const float* mlp_b = (const float*)d_in[6];
  float* out = (float*)d_out;
  float* logits = (float*)d_ws;   // 2*BATCH floats of scratch

  dim3 grid(BATCH, 2);
  knrm_pair_kernel<<<grid, THREADS, 0, stream>>>(q1, d1, q2, d2, emb, mlp_w, mlp_b, logits);
  knrm_combine_kernel<<<(BATCH + 255) / 256, 256, 0, stream>>>(logits, out);
}

// Round 8
// 100.716 us; speedup vs baseline: 1.4817x; 1.4817x over previous
//
#include <hip/hip_runtime.h>
#include <hip/hip_fp16.h>

#define BATCH 4096
#define LQ 30
#define LD 128
#define EMB 50
#define ROWS 160       // rows 0..29 query, 30..31 pad, 32..159 docs
#define KN 21
#define THREADS 512
#define K10 14.426950408889634f      // 10/ln2
#define C50 72.134752044448169f      // 50/ln2
#define KW  144.26950408889634f      // 100/ln2

typedef __attribute__((ext_vector_type(8))) _Float16 half8;
typedef __attribute__((ext_vector_type(4))) float f32x4;

#define EXP2(x) __builtin_amdgcn_exp2f(x)
// LDS layout: row-major [160][64] fp16 (128 B row), XOR-swizzled at 16B chunks.
// uint-unit address of chunk c of row r:
#define SHW(row, c) (((row) << 5) + ((((c) ^ ((row) & 7))) << 2))

// G_j = exp(-j^2/2), j = k-10 (applied once after pooling)
__device__ __constant__ float Gv[20] = {
  1.928749847963918e-22f, 2.576757109154981e-18f, 1.266416554909418e-14f,
  2.269996488124243e-11f, 1.522997974471263e-08f, 3.726653172078671e-06f,
  3.354626279025119e-04f, 1.110899653824231e-02f, 1.353352832366127e-01f,
  6.065306597126334e-01f, 1.0f,
  6.065306597126334e-01f, 1.353352832366127e-01f, 1.110899653824231e-02f,
  3.354626279025119e-04f, 3.726653172078671e-06f, 1.522997974471263e-08f,
  2.269996488124243e-11f, 1.266416554909418e-14f, 2.576757109154981e-18f
};

__device__ __forceinline__ unsigned pack2(float a, float b) {
  __half2 h = __floats2half2_rn(a, b);
  return *reinterpret_cast<unsigned*>(&h);
}

__global__ __launch_bounds__(THREADS, 4) void knrm_pair_kernel(
    const int* __restrict__ q1, const int* __restrict__ d1,
    const int* __restrict__ q2, const int* __restrict__ d2,
    const float* __restrict__ emb, const float* __restrict__ mlp_w,
    const float* __restrict__ mlp_b, float* __restrict__ logits)
{
  __shared__ unsigned int shw[ROWS * 32];        // 160 rows x 64 fp16 (swizzled)
  __shared__ int toks[ROWS];
  __shared__ float kacc2[2][4][16][KN];          // [qtile][dpair][qcol][kernel]

  const int b = blockIdx.x;
  const int pair = blockIdx.y;
  const int tid = threadIdx.x;
  const int* __restrict__ qp = pair ? q2 : q1;
  const int* __restrict__ dp = pair ? d2 : d1;

  // ---- token ids ----
  if (tid < ROWS) {
    int t = -1;
    if (tid < LQ) t = qp[b * LQ + tid];
    else if (tid >= 32) t = dp[b * LD + (tid - 32)];
    toks[tid] = t;
  }
  __syncthreads();

  // ---- phase 1: 2 threads per row; gather + normalize + fp16 store ----
  if (tid < 2 * ROWS) {
    const int row = tid >> 1;
    const int p = tid & 1;                // p=0: elems 0..23, p=1: 24..49
    const int tok = toks[row];
    float4 e[6];
    float2 tail = make_float2(0.f, 0.f);
    float ss = 0.f;
    if (tok >= 0) {
      const float* bp = emb + (long)tok * EMB + p * 24;
      #pragma unroll
      for (int c = 0; c < 6; ++c) e[c] = *(const float4*)(bp + 4 * c);
      if (p) tail = *(const float2*)(emb + (long)tok * EMB + 48);
      #pragma unroll
      for (int c = 0; c < 6; ++c)
        ss += e[c].x*e[c].x + e[c].y*e[c].y + e[c].z*e[c].z + e[c].w*e[c].w;
      ss += tail.x*tail.x + tail.y*tail.y;
    } else {
      #pragma unroll
      for (int c = 0; c < 6; ++c) e[c] = make_float4(0.f, 0.f, 0.f, 0.f);
    }
    ss += __shfl_xor(ss, 1);
    const float scale = 1.0f / fmaxf(sqrtf(ss), 1e-12f);
    #pragma unroll
    for (int cc = 0; cc < 3; ++cc) {      // 3 full 16B chunks (8 halfs each)
      const float4 a = e[2 * cc], b4 = e[2 * cc + 1];
      uint4 w4;
      w4.x = pack2(a.x * scale, a.y * scale);
      w4.y = pack2(a.z * scale, a.w * scale);
      w4.z = pack2(b4.x * scale, b4.y * scale);
      w4.w = pack2(b4.z * scale, b4.w * scale);
      *(uint4*)&shw[SHW(row, p * 3 + cc)] = w4;
    }
    if (p) {                              // chunk 6: elems 48,49 + zeros; chunk 7: zeros
      uint4 t6 = {pack2(tail.x * scale, tail.y * scale), 0u, 0u, 0u};
      *(uint4*)&shw[SHW(row, 6)] = t6;
      uint4 z = {0u, 0u, 0u, 0u};
      *(uint4*)&shw[SHW(row, 7)] = z;
    }
  }
  __syncthreads();

  // ---- phase 2: wave w = (qtile, dpair); 2 doc-tiles per wave ----
  const int lane = tid & 63;
  const int w = tid >> 6;             // 0..7
  const int qtile = w >> 2;           // 0..1
  const int dpair = w & 3;            // 0..3  -> dtiles {dpair, dpair+4}
  const int col = lane & 15;          // C col = query within tile
  const int kgrp = lane >> 4;         // 0..3

  const int qrow = qtile * 16 + col;
  const half8 Bq0 = *(const half8*)&shw[SHW(qrow, kgrp)];       // k 0..31 slice
  const half8 Bq1 = *(const half8*)&shw[SHW(qrow, 4 + kgrp)];   // k 32..63 slice
  const int qtok = toks[qrow];

  // doc tokens for this lane's 8 output rows (hoisted)
  int dt8[8];
  #pragma unroll
  for (int s = 0; s < 2; ++s)
    #pragma unroll
    for (int r = 0; r < 4; ++r)
      dt8[s * 4 + r] = toks[32 + (dpair + s * 4) * 16 + kgrp * 4 + r];

  float macc[20];                     // unscaled power sums  sum v*T^j, j=k-10
  #pragma unroll
  for (int k = 0; k < 20; ++k) macc[k] = 0.0f;
  float cnt = 0.0f;

  #pragma unroll 1
  for (int s = 0; s < 2; ++s) {
    const int arow = 32 + (dpair + s * 4) * 16 + col;   // A row = doc
    const half8 A0 = *(const half8*)&shw[SHW(arow, kgrp)];
    const half8 A1 = *(const half8*)&shw[SHW(arow, 4 + kgrp)];

    f32x4 acc = {0.0f, 0.0f, 0.0f, 0.0f};
    acc = __builtin_amdgcn_mfma_f32_16x16x32_f16(A0, Bq0, acc, 0, 0, 0);
    acc = __builtin_amdgcn_mfma_f32_16x16x32_f16(A1, Bq1, acc, 0, 0, 0);

    #pragma unroll
    for (int r = 0; r < 4; ++r) {
      const float x = acc[r];
      cnt += (dt8[s * 4 + r] == qtok) ? 1.0f : 0.0f;  // exact-match kernel
      const float t  = x - 0.05f;
      const float tt = t * t;
      const float varg = -C50 * tt;
      const float v = EXP2(varg);                 // e^{-50 t^2}      (j=0)
      const float T = EXP2(K10 * t);              // e^{10 t}
      const float wd = EXP2(fmaf(-KW, t, varg));  // v*T^-10          (j=-10)
      const float T2 = T * T, T3 = T2 * T, T4 = T2 * T2;
      macc[10] += v;
      macc[11] = fmaf(v, T,  macc[11]);
      macc[12] = fmaf(v, T2, macc[12]);
      macc[13] = fmaf(v, T3, macc[13]);
      float pu = v * T4;                          // j=4
      macc[14] += pu;
      macc[15] = fmaf(pu, T,  macc[15]);
      macc[16] = fmaf(pu, T2, macc[16]);
      macc[17] = fmaf(pu, T3, macc[17]);
      pu *= T4;                                   // j=8
      macc[18] += pu;
      macc[19] = fmaf(pu, T,  macc[19]);
      macc[0] += wd;
      macc[1] = fmaf(wd, T,  macc[1]);
      macc[2] = fmaf(wd, T2, macc[2]);
      macc[3] = fmaf(wd, T3, macc[3]);
      float qd = wd * T4;                         // j=-6
      macc[4] += qd;
      macc[5] = fmaf(qd, T,  macc[5]);
      macc[6] = fmaf(qd, T2, macc[6]);
      macc[7] = fmaf(qd, T3, macc[7]);
      qd *= T4;                                   // j=-2
      macc[8] += qd;
      macc[9] = fmaf(qd, T,  macc[9]);
    }
  }

  // cross-kgrp (doc) reduction within the wave, then G_j scaling
  float out_r[KN];
  #pragma unroll
  for (int k = 0; k < 20; ++k) out_r[k] = macc[k];
  out_r[20] = cnt;
  #pragma unroll
  for (int k = 0; k < KN; ++k) {
    out_r[k] += __shfl_xor(out_r[k], 16);
    out_r[k] += __shfl_xor(out_r[k], 32);
  }

  if (lane < 16) {
    #pragma unroll
    for (int k = 0; k < 20; ++k)
      kacc2[qtile][dpair][lane][k] = out_r[k] * Gv[k];
    kacc2[qtile][dpair][lane][20] = out_r[20];
  }
  __syncthreads();

  // ---- final: wave 0 combines 4 doc-slices, applies log1p + MLP ----
  if (tid < 64) {
    float s = 0.0f;
    if (tid < 32) {
      const int qt = tid >> 4, q = tid & 15;
      if (qt * 16 + q < LQ) {
        #pragma unroll
        for (int k = 0; k < KN; ++k) {
          const float S = kacc2[qt][0][q][k] + kacc2[qt][1][q][k] +
                          kacc2[qt][2][q][k] + kacc2[qt][3][q][k];
          s = fmaf(mlp_w[k], __logf(1.0f + S), s);
        }
      }
    }
    s += __shfl_xor(s, 1);
    s += __shfl_xor(s, 2);
    s += __shfl_xor(s, 4);
    s += __shfl_xor(s, 8);
    s += __shfl_xor(s, 16);
    s += __shfl_xor(s, 32);
    if (tid == 0) logits[pair * BATCH + b] = s + mlp_b[0];
  }
}

__global__ void knrm_combine_kernel(const float* __restrict__ logits,
                                    float* __restrict__ out) {
  int i = blockIdx.x * 256 + threadIdx.x;
  if (i < BATCH) {
    float z = logits[i] - logits[BATCH + i];
    out[i] = 1.0f / (1.0f + __expf(-z));
  }
}

extern "C" void kernel_launch(void* const* d_in, const int* in_sizes, int n_in,
                              void* d_out, int out_size, void* d_ws, size_t ws_size,
                              hipStream_t stream) {
  const int* q1 = (const int*)d_in[0];
  const int* d1 = (const int*)d_in[1];
  const int* q2 = (const int*)d_in[2];
  const int* d2 = (const int*)d_in[3];
  const float* emb = (const float*)d_in[4];
  const float* mlp_w = (const float*)d_in[5];
  const float* mlp_b = (const float*)d_in[6];
  float* out = (float*)d_out;
  float* logits = (float*)d_ws;   // 2*BATCH floats of scratch

  dim3 grid(BATCH, 2);
  knrm_pair_kernel<<<grid, THREADS, 0, stream>>>(q1, d1, q2, d2, emb, mlp_w, mlp_b, logits);
  knrm_combine_kernel<<<(BATCH + 255) / 256, 256, 0, stream>>>(logits, out);
}

// Round 9
// 84.596 us; speedup vs baseline: 1.7640x; 1.1906x over previous
//
#include <hip/hip_runtime.h>
#include <hip/hip_fp16.h>

#define BATCH 4096
#define LQ 30
#define LD 128
#define EMB 50
#define ROWS 160       // rows 0..29 query, 30..31 pad, 32..159 docs
#define KN 21
#define THREADS 512
#define K10 14.426950408889634f      // 10/ln2
#define C50 72.134752044448169f      // 50/ln2
#define KW  144.26950408889634f      // 100/ln2

typedef __attribute__((ext_vector_type(8))) _Float16 half8;
typedef __attribute__((ext_vector_type(4))) float f32x4;

#define EXP2(x) __builtin_amdgcn_exp2f(x)
// LDS layout: row-major [160][64] fp16 (128 B row), XOR-swizzled at 16B chunks.
// uint-unit address of chunk c of row r:
#define SHW(row, c) (((row) << 5) + ((((c) ^ ((row) & 7))) << 2))

// G_j = exp(-j^2/2), j = k-10 (applied once after pooling)
__device__ __constant__ float Gv[20] = {
  1.928749847963918e-22f, 2.576757109154981e-18f, 1.266416554909418e-14f,
  2.269996488124243e-11f, 1.522997974471263e-08f, 3.726653172078671e-06f,
  3.354626279025119e-04f, 1.110899653824231e-02f, 1.353352832366127e-01f,
  6.065306597126334e-01f, 1.0f,
  6.065306597126334e-01f, 1.353352832366127e-01f, 1.110899653824231e-02f,
  3.354626279025119e-04f, 3.726653172078671e-06f, 1.522997974471263e-08f,
  2.269996488124243e-11f, 1.266416554909418e-14f, 2.576757109154981e-18f
};

__device__ __forceinline__ unsigned pack2(float a, float b) {
  __half2 h = __floats2half2_rn(a, b);
  return *reinterpret_cast<unsigned*>(&h);
}

__global__ __launch_bounds__(THREADS, 4) void knrm_pair_kernel(
    const int* __restrict__ q1, const int* __restrict__ d1,
    const int* __restrict__ q2, const int* __restrict__ d2,
    const float* __restrict__ emb, const float* __restrict__ mlp_w,
    const float* __restrict__ mlp_b, float* __restrict__ logits)
{
  __shared__ unsigned int shw[ROWS * 32];        // 160 rows x 64 fp16 (swizzled)
  __shared__ int toks[ROWS];
  __shared__ float kacc2[2][4][16][KN];          // [qtile][dpair][qcol][kernel]

  const int b = blockIdx.x;
  const int pair = blockIdx.y;
  const int tid = threadIdx.x;
  const int* __restrict__ qp = pair ? q2 : q1;
  const int* __restrict__ dp = pair ? d2 : d1;

  // ---- token ids ----
  if (tid < ROWS) {
    int t = -1;
    if (tid < LQ) t = qp[b * LQ + tid];
    else if (tid >= 32) t = dp[b * LD + (tid - 32)];
    toks[tid] = t;
  }
  __syncthreads();

  // ---- phase 1: 2 threads per row; gather + normalize + fp16 store ----
  if (tid < 2 * ROWS) {
    const int row = tid >> 1;
    const int p = tid & 1;                // p=0: elems 0..23, p=1: 24..49
    const int tok = toks[row];
    float4 e[6];
    float2 tail = make_float2(0.f, 0.f);
    float ss = 0.f;
    if (tok >= 0) {
      const float* bp = emb + (long)tok * EMB + p * 24;
      #pragma unroll
      for (int c = 0; c < 6; ++c) e[c] = *(const float4*)(bp + 4 * c);
      if (p) tail = *(const float2*)(emb + (long)tok * EMB + 48);
      #pragma unroll
      for (int c = 0; c < 6; ++c)
        ss += e[c].x*e[c].x + e[c].y*e[c].y + e[c].z*e[c].z + e[c].w*e[c].w;
      ss += tail.x*tail.x + tail.y*tail.y;
    } else {
      #pragma unroll
      for (int c = 0; c < 6; ++c) e[c] = make_float4(0.f, 0.f, 0.f, 0.f);
    }
    ss += __shfl_xor(ss, 1);
    const float scale = 1.0f / fmaxf(sqrtf(ss), 1e-12f);
    #pragma unroll
    for (int cc = 0; cc < 3; ++cc) {      // 3 full 16B chunks (8 halfs each)
      const float4 a = e[2 * cc], b4 = e[2 * cc + 1];
      uint4 w4;
      w4.x = pack2(a.x * scale, a.y * scale);
      w4.y = pack2(a.z * scale, a.w * scale);
      w4.z = pack2(b4.x * scale, b4.y * scale);
      w4.w = pack2(b4.z * scale, b4.w * scale);
      *(uint4*)&shw[SHW(row, p * 3 + cc)] = w4;
    }
    if (p) {                              // chunk 6: elems 48,49 + zeros; chunk 7: zeros
      uint4 t6 = {pack2(tail.x * scale, tail.y * scale), 0u, 0u, 0u};
      *(uint4*)&shw[SHW(row, 6)] = t6;
      uint4 z = {0u, 0u, 0u, 0u};
      *(uint4*)&shw[SHW(row, 7)] = z;
    }
  }
  __syncthreads();

  // ---- phase 2: wave w = (qtile, dpair); 2 doc-tiles per wave ----
  const int lane = tid & 63;
  const int w = tid >> 6;             // 0..7
  const int qtile = w >> 2;           // 0..1
  const int dpair = w & 3;            // 0..3  -> dtiles {dpair, dpair+4}
  const int col = lane & 15;          // C col = query within tile
  const int kgrp = lane >> 4;         // 0..3

  const int qrow = qtile * 16 + col;
  const half8 Bq0 = *(const half8*)&shw[SHW(qrow, kgrp)];       // k 0..31 slice
  const half8 Bq1 = *(const half8*)&shw[SHW(qrow, 4 + kgrp)];   // k 32..63 slice
  const int qtok = toks[qrow];

  float macc[20];                     // unscaled power sums  sum v*T^j, j=k-10
  #pragma unroll
  for (int k = 0; k < 20; ++k) macc[k] = 0.0f;
  float cnt = 0.0f;

  #pragma unroll 1
  for (int s = 0; s < 2; ++s) {
    const int arow = 32 + (dpair + s * 4) * 16 + col;   // A row = doc
    const half8 A0 = *(const half8*)&shw[SHW(arow, kgrp)];
    const half8 A1 = *(const half8*)&shw[SHW(arow, 4 + kgrp)];

    f32x4 acc = {0.0f, 0.0f, 0.0f, 0.0f};
    acc = __builtin_amdgcn_mfma_f32_16x16x32_f16(A0, Bq0, acc, 0, 0, 0);
    acc = __builtin_amdgcn_mfma_f32_16x16x32_f16(A1, Bq1, acc, 0, 0, 0);

    const int dbase = 32 + (dpair + s * 4) * 16 + kgrp * 4;  // C rows = docs
    #pragma unroll
    for (int r = 0; r < 4; ++r) {
      const float x = acc[r];
      cnt += (toks[dbase + r] == qtok) ? 1.0f : 0.0f;  // exact-match kernel
      const float t  = x - 0.05f;
      const float tt = t * t;
      const float varg = -C50 * tt;
      const float v = EXP2(varg);                 // e^{-50 t^2}      (j=0)
      const float T = EXP2(K10 * t);              // e^{10 t}
      const float wd = EXP2(fmaf(-KW, t, varg));  // v*T^-10          (j=-10)
      const float T2 = T * T, T3 = T2 * T, T4 = T2 * T2;
      macc[10] += v;
      macc[11] = fmaf(v, T,  macc[11]);
      macc[12] = fmaf(v, T2, macc[12]);
      macc[13] = fmaf(v, T3, macc[13]);
      float pu = v * T4;                          // j=4
      macc[14] += pu;
      macc[15] = fmaf(pu, T,  macc[15]);
      macc[16] = fmaf(pu, T2, macc[16]);
      macc[17] = fmaf(pu, T3, macc[17]);
      pu *= T4;                                   // j=8
      macc[18] += pu;
      macc[19] = fmaf(pu, T,  macc[19]);
      macc[0] += wd;
      macc[1] = fmaf(wd, T,  macc[1]);
      macc[2] = fmaf(wd, T2, macc[2]);
      macc[3] = fmaf(wd, T3, macc[3]);
      float qd = wd * T4;                         // j=-6
      macc[4] += qd;
      macc[5] = fmaf(qd, T,  macc[5]);
      macc[6] = fmaf(qd, T2, macc[6]);
      macc[7] = fmaf(qd, T3, macc[7]);
      qd *= T4;                                   // j=-2
      macc[8] += qd;
      macc[9] = fmaf(qd, T,  macc[9]);
    }
  }

  // cross-kgrp (doc) reduction within the wave, then G_j scaling
  float out_r[KN];
  #pragma unroll
  for (int k = 0; k < 20; ++k) out_r[k] = macc[k];
  out_r[20] = cnt;
  #pragma unroll
  for (int k = 0; k < KN; ++k) {
    out_r[k] += __shfl_xor(out_r[k], 16);
    out_r[k] += __shfl_xor(out_r[k], 32);
  }

  if (lane < 16) {
    #pragma unroll
    for (int k = 0; k < 20; ++k)
      kacc2[qtile][dpair][lane][k] = out_r[k] * Gv[k];
    kacc2[qtile][dpair][lane][20] = out_r[20];
  }
  __syncthreads();

  // ---- final: wave 0 combines 4 doc-slices, applies log1p + MLP ----
  if (tid < 64) {
    float s = 0.0f;
    if (tid < 32) {
      const int qt = tid >> 4, q = tid & 15;
      if (qt * 16 + q < LQ) {
        #pragma unroll
        for (int k = 0; k < KN; ++k) {
          const float S = kacc2[qt][0][q][k] + kacc2[qt][1][q][k] +
                          kacc2[qt][2][q][k] + kacc2[qt][3][q][k];
          s = fmaf(mlp_w[k], __logf(1.0f + S), s);
        }
      }
    }
    s += __shfl_xor(s, 1);
    s += __shfl_xor(s, 2);
    s += __shfl_xor(s, 4);
    s += __shfl_xor(s, 8);
    s += __shfl_xor(s, 16);
    s += __shfl_xor(s, 32);
    if (tid == 0) logits[pair * BATCH + b] = s + mlp_b[0];
  }
}

__global__ void knrm_combine_kernel(const float* __restrict__ logits,
                                    float* __restrict__ out) {
  int i = blockIdx.x * 256 + threadIdx.x;
  if (i < BATCH) {
    float z = logits[i] - logits[BATCH + i];
    out[i] = 1.0f / (1.0f + __expf(-z));
  }
}

extern "C" void kernel_launch(void* const* d_in, const int* in_sizes, int n_in,
                              void* d_out, int out_size, void* d_ws, size_t ws_size,
                              hipStream_t stream) {
  const int* q1 = (const int*)d_in[0];
  const int* d1 = (const int*)d_in[1];
  const int* q2 = (const int*)d_in[2];
  const int* d2 = (const int*)d_in[3];
  const float* emb = (const float*)d_in[4];
  const float* mlp_w = (const float*)d_in[5];
  const float* mlp_b = (const float*)d_in[6];
  float* out = (float*)d_out;
  float* logits = (float*)d_ws;   // 2*BATCH floats of scratch

  dim3 grid(BATCH, 2);
  knrm_pair_kernel<<<grid, THREADS, 0, stream>>>(q1, d1, q2, d2, emb, mlp_w, mlp_b, logits);
  knrm_combine_kernel<<<(BATCH + 255) / 256, 256, 0, stream>>>(logits, out);
}

// Round 10
// 79.698 us; speedup vs baseline: 1.8724x; 1.0615x over previous
//
#include <hip/hip_runtime.h>
#include <hip/hip_fp16.h>

#define BATCH 4096
#define LQ 30
#define LD 128
#define EMB 50
#define ROWS 160       // rows 0..29 query, 30..31 pad, 32..159 docs
#define KN 21
#define THREADS 512
#define K10 14.426950408889634f      // 10/ln2
#define C50 72.134752044448169f      // 50/ln2
#define KW  144.26950408889634f      // 100/ln2

typedef __attribute__((ext_vector_type(8))) _Float16 half8;
typedef __attribute__((ext_vector_type(4))) float f32x4;

#define EXP2(x) __builtin_amdgcn_exp2f(x)
// LDS layout: row-major [160][64] fp16 (128 B row), XOR-swizzled at 16B chunks.
// uint-unit address of chunk c of row r:
#define SHW(row, c) (((row) << 5) + ((((c) ^ ((row) & 7))) << 2))

// G_j = exp(-j^2/2), j = k-10 (applied once after pooling)
__device__ __constant__ float Gv[20] = {
  1.928749847963918e-22f, 2.576757109154981e-18f, 1.266416554909418e-14f,
  2.269996488124243e-11f, 1.522997974471263e-08f, 3.726653172078671e-06f,
  3.354626279025119e-04f, 1.110899653824231e-02f, 1.353352832366127e-01f,
  6.065306597126334e-01f, 1.0f,
  6.065306597126334e-01f, 1.353352832366127e-01f, 1.110899653824231e-02f,
  3.354626279025119e-04f, 3.726653172078671e-06f, 1.522997974471263e-08f,
  2.269996488124243e-11f, 1.266416554909418e-14f, 2.576757109154981e-18f
};

__device__ __forceinline__ unsigned pack2(float a, float b) {
  __half2 h = __floats2half2_rn(a, b);
  return *reinterpret_cast<unsigned*>(&h);
}

__global__ __launch_bounds__(THREADS, 6) void knrm_pair_kernel(
    const int* __restrict__ q1, const int* __restrict__ d1,
    const int* __restrict__ q2, const int* __restrict__ d2,
    const float* __restrict__ emb, const float* __restrict__ mlp_w,
    const float* __restrict__ mlp_b, float* __restrict__ logits)
{
  __shared__ unsigned int shw[ROWS * 32];        // 160 rows x 64 fp16 (swizzled)
  __shared__ int toks[ROWS];
  __shared__ float kacc2[2][4][16][KN];          // [qtile][dpair][qcol][kernel]

  const int b = blockIdx.x;
  const int pair = blockIdx.y;
  const int tid = threadIdx.x;
  const int* __restrict__ qp = pair ? q2 : q1;
  const int* __restrict__ dp = pair ? d2 : d1;

  // ---- token ids ----
  if (tid < ROWS) {
    int t = -1;
    if (tid < LQ) t = qp[b * LQ + tid];
    else if (tid >= 32) t = dp[b * LD + (tid - 32)];
    toks[tid] = t;
  }
  __syncthreads();

  // ---- phase 1: 2 threads per row; gather + normalize + fp16 store ----
  if (tid < 2 * ROWS) {
    const int row = tid >> 1;
    const int p = tid & 1;                // p=0: elems 0..23, p=1: 24..49
    const int tok = toks[row];
    float4 e[6];
    float2 tail = make_float2(0.f, 0.f);
    float ss = 0.f;
    if (tok >= 0) {
      const float* bp = emb + (long)tok * EMB + p * 24;
      #pragma unroll
      for (int c = 0; c < 6; ++c) e[c] = *(const float4*)(bp + 4 * c);
      if (p) tail = *(const float2*)(emb + (long)tok * EMB + 48);
      #pragma unroll
      for (int c = 0; c < 6; ++c)
        ss += e[c].x*e[c].x + e[c].y*e[c].y + e[c].z*e[c].z + e[c].w*e[c].w;
      ss += tail.x*tail.x + tail.y*tail.y;
    } else {
      #pragma unroll
      for (int c = 0; c < 6; ++c) e[c] = make_float4(0.f, 0.f, 0.f, 0.f);
    }
    ss += __shfl_xor(ss, 1);
    const float scale = 1.0f / fmaxf(sqrtf(ss), 1e-12f);
    #pragma unroll
    for (int cc = 0; cc < 3; ++cc) {      // 3 full 16B chunks (8 halfs each)
      const float4 a = e[2 * cc], b4 = e[2 * cc + 1];
      uint4 w4;
      w4.x = pack2(a.x * scale, a.y * scale);
      w4.y = pack2(a.z * scale, a.w * scale);
      w4.z = pack2(b4.x * scale, b4.y * scale);
      w4.w = pack2(b4.z * scale, b4.w * scale);
      *(uint4*)&shw[SHW(row, p * 3 + cc)] = w4;
    }
    if (p) {                              // chunk 6: elems 48,49 + zeros; chunk 7: zeros
      uint4 t6 = {pack2(tail.x * scale, tail.y * scale), 0u, 0u, 0u};
      *(uint4*)&shw[SHW(row, 6)] = t6;
      uint4 z = {0u, 0u, 0u, 0u};
      *(uint4*)&shw[SHW(row, 7)] = z;
    }
  }
  __syncthreads();

  // ---- phase 2: wave w = (qtile, dpair); 2 doc-tiles per wave ----
  const int lane = tid & 63;
  const int w = tid >> 6;             // 0..7
  const int qtile = w >> 2;           // 0..1
  const int dpair = w & 3;            // 0..3  -> dtiles {dpair, dpair+4}
  const int col = lane & 15;          // C col = query within tile
  const int kgrp = lane >> 4;         // 0..3

  const int qrow = qtile * 16 + col;
  const half8 Bq0 = *(const half8*)&shw[SHW(qrow, kgrp)];       // k 0..31 slice
  const half8 Bq1 = *(const half8*)&shw[SHW(qrow, 4 + kgrp)];   // k 32..63 slice
  const int qtok = toks[qrow];

  float macc[20];                     // unscaled power sums  sum v*T^j, j=k-10
  #pragma unroll
  for (int k = 0; k < 20; ++k) macc[k] = 0.0f;
  float cnt = 0.0f;

  #pragma unroll
  for (int s = 0; s < 2; ++s) {
    const int arow = 32 + (dpair + s * 4) * 16 + col;   // A row = doc
    const half8 A0 = *(const half8*)&shw[SHW(arow, kgrp)];
    const half8 A1 = *(const half8*)&shw[SHW(arow, 4 + kgrp)];

    f32x4 acc = {0.0f, 0.0f, 0.0f, 0.0f};
    acc = __builtin_amdgcn_mfma_f32_16x16x32_f16(A0, Bq0, acc, 0, 0, 0);
    acc = __builtin_amdgcn_mfma_f32_16x16x32_f16(A1, Bq1, acc, 0, 0, 0);

    const int dbase = 32 + (dpair + s * 4) * 16 + kgrp * 4;  // C rows = docs
    #pragma unroll
    for (int r = 0; r < 4; ++r) {
      const float x = acc[r];
      cnt += (toks[dbase + r] == qtok) ? 1.0f : 0.0f;  // exact-match kernel
      const float t  = x - 0.05f;
      const float tt = t * t;
      const float varg = -C50 * tt;
      const float v = EXP2(varg);                 // e^{-50 t^2}      (j=0)
      const float T = EXP2(K10 * t);              // e^{10 t}
      const float wd = EXP2(fmaf(-KW, t, varg));  // v*T^-10          (j=-10)
      const float T2 = T * T, T3 = T2 * T, T4 = T2 * T2;
      macc[10] += v;
      macc[11] = fmaf(v, T,  macc[11]);
      macc[12] = fmaf(v, T2, macc[12]);
      macc[13] = fmaf(v, T3, macc[13]);
      float pu = v * T4;                          // j=4
      macc[14] += pu;
      macc[15] = fmaf(pu, T,  macc[15]);
      macc[16] = fmaf(pu, T2, macc[16]);
      macc[17] = fmaf(pu, T3, macc[17]);
      pu *= T4;                                   // j=8
      macc[18] += pu;
      macc[19] = fmaf(pu, T,  macc[19]);
      macc[0] += wd;
      macc[1] = fmaf(wd, T,  macc[1]);
      macc[2] = fmaf(wd, T2, macc[2]);
      macc[3] = fmaf(wd, T3, macc[3]);
      float qd = wd * T4;                         // j=-6
      macc[4] += qd;
      macc[5] = fmaf(qd, T,  macc[5]);
      macc[6] = fmaf(qd, T2, macc[6]);
      macc[7] = fmaf(qd, T3, macc[7]);
      qd *= T4;                                   // j=-2
      macc[8] += qd;
      macc[9] = fmaf(qd, T,  macc[9]);
    }
  }

  // cross-kgrp (doc) reduction within the wave, then G_j scaling
  float out_r[KN];
  #pragma unroll
  for (int k = 0; k < 20; ++k) out_r[k] = macc[k];
  out_r[20] = cnt;
  #pragma unroll
  for (int k = 0; k < KN; ++k) {
    out_r[k] += __shfl_xor(out_r[k], 16);
    out_r[k] += __shfl_xor(out_r[k], 32);
  }

  if (lane < 16) {
    #pragma unroll
    for (int k = 0; k < 20; ++k)
      kacc2[qtile][dpair][lane][k] = out_r[k] * Gv[k];
    kacc2[qtile][dpair][lane][20] = out_r[20];
  }
  __syncthreads();

  // ---- final: wave 0 combines 4 doc-slices, applies log1p + MLP ----
  if (tid < 64) {
    float s = 0.0f;
    if (tid < 32) {
      const int qt = tid >> 4, q = tid & 15;
      if (qt * 16 + q < LQ) {
        #pragma unroll
        for (int k = 0; k < KN; ++k) {
          const float S = kacc2[qt][0][q][k] + kacc2[qt][1][q][k] +
                          kacc2[qt][2][q][k] + kacc2[qt][3][q][k];
          s = fmaf(mlp_w[k], __logf(1.0f + S), s);
        }
      }
    }
    s += __shfl_xor(s, 1);
    s += __shfl_xor(s, 2);
    s += __shfl_xor(s, 4);
    s += __shfl_xor(s, 8);
    s += __shfl_xor(s, 16);
    s += __shfl_xor(s, 32);
    if (tid == 0) logits[pair * BATCH + b] = s + mlp_b[0];
  }
}

__global__ void knrm_combine_kernel(const float* __restrict__ logits,
                                    float* __restrict__ out) {
  int i = blockIdx.x * 256 + threadIdx.x;
  if (i < BATCH) {
    float z = logits[i] - logits[BATCH + i];
    out[i] = 1.0f / (1.0f + __expf(-z));
  }
}

extern "C" void kernel_launch(void* const* d_in, const int* in_sizes, int n_in,
                              void* d_out, int out_size, void* d_ws, size_t ws_size,
                              hipStream_t stream) {
  const int* q1 = (const int*)d_in[0];
  const int* d1 = (const int*)d_in[1];
  const int* q2 = (const int*)d_in[2];
  const int* d2 = (const int*)d_in[3];
  const float* emb = (const float*)d_in[4];
  const float* mlp_w = (const float*)d_in[5];
  const float* mlp_b = (const float*)d_in[6];
  float* out = (float*)d_out;
  float* logits = (float*)d_ws;   // 2*BATCH floats of scratch

  dim3 grid(BATCH, 2);
  knrm_pair_kernel<<<grid, THREADS, 0, stream>>>(q1, d1, q2, d2, emb, mlp_w, mlp_b, logits);
  knrm_combine_kernel<<<(BATCH + 255) / 256, 256, 0, stream>>>(logits, out);
}

// Round 11
// 79.605 us; speedup vs baseline: 1.8746x; 1.0012x over previous
//
#include <hip/hip_runtime.h>
#include <hip/hip_fp16.h>

#define BATCH 4096
#define LQ 30
#define LD 128
#define EMB 50
#define ROWS 160       // rows 0..29 query, 30..31 pad, 32..159 docs
#define KN 21
#define THREADS 512
#define K10 14.426950408889634f      // 10/ln2
#define C50 72.134752044448169f      // 50/ln2
#define KW  144.26950408889634f      // 100/ln2

typedef __attribute__((ext_vector_type(8))) _Float16 half8;
typedef __attribute__((ext_vector_type(4))) float f32x4;

#define EXP2(x) __builtin_amdgcn_exp2f(x)
// LDS layout: row-major [160][64] fp16 (128 B row), XOR-swizzled at 16B chunks.
// uint-unit address of chunk c of row r:
#define SHW(row, c) (((row) << 5) + ((((c) ^ ((row) & 7))) << 2))

// G_j = exp(-j^2/2), j = k-10 (applied once after pooling)
__device__ __constant__ float Gv[20] = {
  1.928749847963918e-22f, 2.576757109154981e-18f, 1.266416554909418e-14f,
  2.269996488124243e-11f, 1.522997974471263e-08f, 3.726653172078671e-06f,
  3.354626279025119e-04f, 1.110899653824231e-02f, 1.353352832366127e-01f,
  6.065306597126334e-01f, 1.0f,
  6.065306597126334e-01f, 1.353352832366127e-01f, 1.110899653824231e-02f,
  3.354626279025119e-04f, 3.726653172078671e-06f, 1.522997974471263e-08f,
  2.269996488124243e-11f, 1.266416554909418e-14f, 2.576757109154981e-18f
};

__device__ __forceinline__ unsigned pack2(float a, float b) {
  __half2 h = __floats2half2_rn(a, b);
  return *reinterpret_cast<unsigned*>(&h);
}

__global__ void knrm_pair_kernel(
    const int* __restrict__ q1, const int* __restrict__ d1,
    const int* __restrict__ q2, const int* __restrict__ d2,
    const float* __restrict__ emb, const float* __restrict__ mlp_w,
    const float* __restrict__ mlp_b, float* __restrict__ logits)
{
  __shared__ unsigned int shw[ROWS * 32];        // 160 rows x 64 fp16 (swizzled)
  __shared__ int toks[ROWS];
  __shared__ float kacc2[2][4][16][KN];          // [qtile][dpair][qcol][kernel]

  const int b = blockIdx.x;
  const int pair = blockIdx.y;
  const int tid = threadIdx.x;
  const int* __restrict__ qp = pair ? q2 : q1;
  const int* __restrict__ dp = pair ? d2 : d1;

  // ---- token ids ----
  if (tid < ROWS) {
    int t = -1;
    if (tid < LQ) t = qp[b * LQ + tid];
    else if (tid >= 32) t = dp[b * LD + (tid - 32)];
    toks[tid] = t;
  }
  __syncthreads();

  // ---- phase 1: 2 threads per row; gather + normalize + fp16 store ----
  if (tid < 2 * ROWS) {
    const int row = tid >> 1;
    const int p = tid & 1;                // p=0: elems 0..23, p=1: 24..49
    const int tok = toks[row];
    float4 e[6];
    float2 tail = make_float2(0.f, 0.f);
    float ss = 0.f;
    if (tok >= 0) {
      const float* bp = emb + (long)tok * EMB + p * 24;
      #pragma unroll
      for (int c = 0; c < 6; ++c) e[c] = *(const float4*)(bp + 4 * c);
      if (p) tail = *(const float2*)(emb + (long)tok * EMB + 48);
      #pragma unroll
      for (int c = 0; c < 6; ++c)
        ss += e[c].x*e[c].x + e[c].y*e[c].y + e[c].z*e[c].z + e[c].w*e[c].w;
      ss += tail.x*tail.x + tail.y*tail.y;
    } else {
      #pragma unroll
      for (int c = 0; c < 6; ++c) e[c] = make_float4(0.f, 0.f, 0.f, 0.f);
    }
    ss += __shfl_xor(ss, 1);
    const float scale = 1.0f / fmaxf(sqrtf(ss), 1e-12f);
    #pragma unroll
    for (int cc = 0; cc < 3; ++cc) {      // 3 full 16B chunks (8 halfs each)
      const float4 a = e[2 * cc], b4 = e[2 * cc + 1];
      uint4 w4;
      w4.x = pack2(a.x * scale, a.y * scale);
      w4.y = pack2(a.z * scale, a.w * scale);
      w4.z = pack2(b4.x * scale, b4.y * scale);
      w4.w = pack2(b4.z * scale, b4.w * scale);
      *(uint4*)&shw[SHW(row, p * 3 + cc)] = w4;
    }
    if (p) {                              // chunk 6: elems 48,49 + zeros; chunk 7: zeros
      uint4 t6 = {pack2(tail.x * scale, tail.y * scale), 0u, 0u, 0u};
      *(uint4*)&shw[SHW(row, 6)] = t6;
      uint4 z = {0u, 0u, 0u, 0u};
      *(uint4*)&shw[SHW(row, 7)] = z;
    }
  }
  __syncthreads();

  // ---- phase 2: wave w = (qtile, dpair); 2 doc-tiles per wave ----
  const int lane = tid & 63;
  const int w = tid >> 6;             // 0..7
  const int qtile = w >> 2;           // 0..1
  const int dpair = w & 3;            // 0..3  -> dtiles {dpair, dpair+4}
  const int col = lane & 15;          // C col = query within tile
  const int kgrp = lane >> 4;         // 0..3

  const int qrow = qtile * 16 + col;
  const half8 Bq0 = *(const half8*)&shw[SHW(qrow, kgrp)];       // k 0..31 slice
  const half8 Bq1 = *(const half8*)&shw[SHW(qrow, 4 + kgrp)];   // k 32..63 slice
  const int qtok = toks[qrow];

  float macc[20];                     // unscaled power sums  sum v*T^j, j=k-10
  #pragma unroll
  for (int k = 0; k < 20; ++k) macc[k] = 0.0f;
  float cnt = 0.0f;

  #pragma unroll
  for (int s = 0; s < 2; ++s) {
    const int arow = 32 + (dpair + s * 4) * 16 + col;   // A row = doc
    const half8 A0 = *(const half8*)&shw[SHW(arow, kgrp)];
    const half8 A1 = *(const half8*)&shw[SHW(arow, 4 + kgrp)];

    f32x4 acc = {0.0f, 0.0f, 0.0f, 0.0f};
    acc = __builtin_amdgcn_mfma_f32_16x16x32_f16(A0, Bq0, acc, 0, 0, 0);
    acc = __builtin_amdgcn_mfma_f32_16x16x32_f16(A1, Bq1, acc, 0, 0, 0);

    const int dbase = 32 + (dpair + s * 4) * 16 + kgrp * 4;  // C rows = docs
    #pragma unroll
    for (int r = 0; r < 4; ++r) {
      const float x = acc[r];
      cnt += (toks[dbase + r] == qtok) ? 1.0f : 0.0f;  // exact-match kernel
      const float t  = x - 0.05f;
      const float tt = t * t;
      const float varg = -C50 * tt;
      const float v = EXP2(varg);                 // e^{-50 t^2}      (j=0)
      const float T = EXP2(K10 * t);              // e^{10 t}
      const float wd = EXP2(fmaf(-KW, t, varg));  // v*T^-10          (j=-10)
      const float T2 = T * T, T3 = T2 * T, T4 = T2 * T2;
      macc[10] += v;
      macc[11] = fmaf(v, T,  macc[11]);
      macc[12] = fmaf(v, T2, macc[12]);
      macc[13] = fmaf(v, T3, macc[13]);
      float pu = v * T4;                          // j=4
      macc[14] += pu;
      macc[15] = fmaf(pu, T,  macc[15]);
      macc[16] = fmaf(pu, T2, macc[16]);
      macc[17] = fmaf(pu, T3, macc[17]);
      pu *= T4;                                   // j=8
      macc[18] += pu;
      macc[19] = fmaf(pu, T,  macc[19]);
      macc[0] += wd;
      macc[1] = fmaf(wd, T,  macc[1]);
      macc[2] = fmaf(wd, T2, macc[2]);
      macc[3] = fmaf(wd, T3, macc[3]);
      float qd = wd * T4;                         // j=-6
      macc[4] += qd;
      macc[5] = fmaf(qd, T,  macc[5]);
      macc[6] = fmaf(qd, T2, macc[6]);
      macc[7] = fmaf(qd, T3, macc[7]);
      qd *= T4;                                   // j=-2
      macc[8] += qd;
      macc[9] = fmaf(qd, T,  macc[9]);
    }
  }

  // cross-kgrp (doc) reduction within the wave, then G_j scaling
  float out_r[KN];
  #pragma unroll
  for (int k = 0; k < 20; ++k) out_r[k] = macc[k];
  out_r[20] = cnt;
  #pragma unroll
  for (int k = 0; k < KN; ++k) {
    out_r[k] += __shfl_xor(out_r[k], 16);
    out_r[k] += __shfl_xor(out_r[k], 32);
  }

  if (lane < 16) {
    #pragma unroll
    for (int k = 0; k < 20; ++k)
      kacc2[qtile][dpair][lane][k] = out_r[k] * Gv[k];
    kacc2[qtile][dpair][lane][20] = out_r[20];
  }
  __syncthreads();

  // ---- final: wave 0 combines 4 doc-slices, applies log1p + MLP ----
  if (tid < 64) {
    float s = 0.0f;
    if (tid < 32) {
      const int qt = tid >> 4, q = tid & 15;
      if (qt * 16 + q < LQ) {
        #pragma unroll
        for (int k = 0; k < KN; ++k) {
          const float S = kacc2[qt][0][q][k] + kacc2[qt][1][q][k] +
                          kacc2[qt][2][q][k] + kacc2[qt][3][q][k];
          s = fmaf(mlp_w[k], __logf(1.0f + S), s);
        }
      }
    }
    s += __shfl_xor(s, 1);
    s += __shfl_xor(s, 2);
    s += __shfl_xor(s, 4);
    s += __shfl_xor(s, 8);
    s += __shfl_xor(s, 16);
    s += __shfl_xor(s, 32);
    if (tid == 0) logits[pair * BATCH + b] = s + mlp_b[0];
  }
}

__global__ void knrm_combine_kernel(const float* __restrict__ logits,
                                    float* __restrict__ out) {
  int i = blockIdx.x * 256 + threadIdx.x;
  if (i < BATCH) {
    float z = logits[i] - logits[BATCH + i];
    out[i] = 1.0f / (1.0f + __expf(-z));
  }
}

extern "C" void kernel_launch(void* const* d_in, const int* in_sizes, int n_in,
                              void* d_out, int out_size, void* d_ws, size_t ws_size,
                              hipStream_t stream) {
  const int* q1 = (const int*)d_in[0];
  const int* d1 = (const int*)d_in[1];
  const int* q2 = (const int*)d_in[2];
  const int* d2 = (const int*)d_in[3];
  const float* emb = (const float*)d_in[4];
  const float* mlp_w = (const float*)d_in[5];
  const float* mlp_b = (const float*)d_in[6];
  float* out = (float*)d_out;
  float* logits = (float*)d_ws;   // 2*BATCH floats of scratch

  dim3 grid(BATCH, 2);
  knrm_pair_kernel<<<grid, THREADS, 0, stream>>>(q1, d1, q2, d2, emb, mlp_w, mlp_b, logits);
  knrm_combine_kernel<<<(BATCH + 255) / 256, 256, 0, stream>>>(logits, out);
}